// Round 3
// baseline (1632.342 us; speedup 1.0000x reference)
//
#include <hip/hip_runtime.h>
#include <hip/hip_bf16.h>

// Problem constants
#define BATCH 8
#define TT    512
#define DM    512
#define NH    8
#define DH    64
#define MM    (BATCH*TT)   // 4096 rows in the projection GEMMs

typedef __attribute__((ext_vector_type(8))) __bf16 bf16x8;
typedef __attribute__((ext_vector_type(4))) float  f32x4;
typedef __attribute__((ext_vector_type(8))) unsigned short u16x8;

union frag_cv { u16x8 u; bf16x8 b; };

// exact bf16->f32
__device__ __forceinline__ float b2f(unsigned short u) {
    union { unsigned int i; float f; } v;
    v.i = ((unsigned int)u) << 16;
    return v.f;
}
// f32->bf16 round-to-nearest-even (inputs finite; no NaN guard needed)
__device__ __forceinline__ unsigned short f2b(float f) {
    union { float f; unsigned int u; } v; v.f = f;
    unsigned int r = v.u + 0x7FFFu + ((v.u >> 16) & 1u);
    return (unsigned short)(r >> 16);
}
// load 8 consecutive floats, convert to bf16x8 MFMA fragment
__device__ __forceinline__ bf16x8 ldf8(const float* p) {
    float4 lo = *(const float4*)p;
    float4 hi = *(const float4*)(p + 4);
    frag_cv c;
    c.u[0] = f2b(lo.x); c.u[1] = f2b(lo.y); c.u[2] = f2b(lo.z); c.u[3] = f2b(lo.w);
    c.u[4] = f2b(hi.x); c.u[5] = f2b(hi.y); c.u[6] = f2b(hi.z); c.u[7] = f2b(hi.w);
    return c.b;
}

// C[M,N] = A[M,K] * B[N,K]^T + bias. A,B,bias are FLOAT32; MFMA in bf16.
// MODE 0: scatter C (bf16) into [B, NH, T, DH] layout, with scale.
// MODE 1: plain row-major [M, N] FLOAT32 output (Cf).
template<int MODE>
__global__ __launch_bounds__(256) void gemm_bt(const float* __restrict__ A,
                                               const float* __restrict__ Bm,
                                               const float* __restrict__ bias,
                                               unsigned short* __restrict__ C,
                                               float* __restrict__ Cf,
                                               float scale) {
    const int K = 512, N = 512;
    int tid  = threadIdx.x;
    int w    = tid >> 6;
    int lane = tid & 63;
    int m0 = blockIdx.y * 64 + (w & 1) * 32;
    int n0 = blockIdx.x * 64 + (w >> 1) * 32;
    int mr = lane & 15;            // fragment row
    int kq = (lane >> 4) * 8;      // k offset within fragment

    f32x4 acc[2][2] = {};
    for (int kk = 0; kk < K; kk += 32) {
        bf16x8 a0 = ldf8(A  + (size_t)(m0      + mr) * K + kk + kq);
        bf16x8 a1 = ldf8(A  + (size_t)(m0 + 16 + mr) * K + kk + kq);
        bf16x8 b0 = ldf8(Bm + (size_t)(n0      + mr) * K + kk + kq);
        bf16x8 b1 = ldf8(Bm + (size_t)(n0 + 16 + mr) * K + kk + kq);
        acc[0][0] = __builtin_amdgcn_mfma_f32_16x16x32_bf16(a0, b0, acc[0][0], 0, 0, 0);
        acc[0][1] = __builtin_amdgcn_mfma_f32_16x16x32_bf16(a0, b1, acc[0][1], 0, 0, 0);
        acc[1][0] = __builtin_amdgcn_mfma_f32_16x16x32_bf16(a1, b0, acc[1][0], 0, 0, 0);
        acc[1][1] = __builtin_amdgcn_mfma_f32_16x16x32_bf16(a1, b1, acc[1][1], 0, 0, 0);
    }

    // C/D layout (verified m89/m91): col = lane&15, row = (lane>>4)*4 + reg
    int rq = (lane >> 4) * 4;
    int cc = lane & 15;
    #pragma unroll
    for (int i = 0; i < 2; ++i) {
        #pragma unroll
        for (int j = 0; j < 2; ++j) {
            int col = n0 + j * 16 + cc;
            float bv = bias[col];
            #pragma unroll
            for (int r = 0; r < 4; ++r) {
                int row = m0 + i * 16 + rq + r;
                float v = (acc[i][j][r] + bv) * scale;
                if (MODE == 0) {
                    int bb = row >> 9, tt2 = row & 511;
                    int hh = col >> 6, dd  = col & 63;
                    C[((size_t)(bb * NH + hh) * TT + tt2) * DH + dd] = f2b(v);
                } else {
                    Cf[(size_t)row * N + col] = v;
                }
            }
        }
    }
}

// One block per (h, t). Handles all B=8 batches so rel_emb is streamed once.
// score[b,s] = sum_d Q[b,h,t,d] * (K[b,h,s,d] + rel[t,s,h*64+d])   (Q pre-scaled by 1/8)
// Q,K,V are bf16 bits (u16); rel is FLOAT32.
__global__ __launch_bounds__(256) void attn_kernel(const unsigned short* __restrict__ Q,
                                                   const unsigned short* __restrict__ K,
                                                   const unsigned short* __restrict__ V,
                                                   const float* __restrict__ rel,
                                                   unsigned short* __restrict__ ctx) {
    __shared__ float qs[BATCH][DH];     // 2 KB
    __shared__ float sc[BATCH][TT];     // 16 KB

    int h = blockIdx.x >> 9;
    int t = blockIdx.x & 511;
    int tid = threadIdx.x;

    for (int idx = tid; idx < BATCH * DH; idx += 256) {
        int b = idx >> 6, d = idx & 63;
        qs[b][d] = b2f(Q[((size_t)(b * NH + h) * TT + t) * DH + d]);
    }
    __syncthreads();

    // Scores: thread -> (b = tid>>5, s = (tid&31) + 32*jj)
    {
        int b  = tid >> 5;
        int s0 = tid & 31;
        const float* relbase = rel + ((size_t)t * TT) * DM + h * DH;
        const unsigned short* kbase = K + (size_t)(b * NH + h) * TT * DH;
        #pragma unroll 2
        for (int jj = 0; jj < 16; ++jj) {
            int s = s0 + 32 * jj;
            const unsigned short* kp = kbase + (size_t)s * DH;
            const float* rp = relbase + (size_t)s * DM;
            float acc = 0.f;
            #pragma unroll
            for (int c = 0; c < 8; ++c) {
                u16x8 kv = *(const u16x8*)(kp + c * 8);
                float4 r0 = *(const float4*)(rp + c * 8);
                float4 r1 = *(const float4*)(rp + c * 8 + 4);
                acc += (b2f(kv[0]) + r0.x) * qs[b][c * 8 + 0];
                acc += (b2f(kv[1]) + r0.y) * qs[b][c * 8 + 1];
                acc += (b2f(kv[2]) + r0.z) * qs[b][c * 8 + 2];
                acc += (b2f(kv[3]) + r0.w) * qs[b][c * 8 + 3];
                acc += (b2f(kv[4]) + r1.x) * qs[b][c * 8 + 4];
                acc += (b2f(kv[5]) + r1.y) * qs[b][c * 8 + 5];
                acc += (b2f(kv[6]) + r1.z) * qs[b][c * 8 + 6];
                acc += (b2f(kv[7]) + r1.w) * qs[b][c * 8 + 7];
            }
            sc[b][s] = acc;
        }
    }
    __syncthreads();

    int w = tid >> 6, lane = tid & 63;

    // Softmax per batch row; wave w handles b = w and b = w+4
    for (int b = w; b < BATCH; b += 4) {
        float x[8], m = -1e30f;
        #pragma unroll
        for (int i = 0; i < 8; ++i) { x[i] = sc[b][lane + 64 * i]; m = fmaxf(m, x[i]); }
        #pragma unroll
        for (int off = 32; off; off >>= 1) m = fmaxf(m, __shfl_xor(m, off));
        float sum = 0.f;
        #pragma unroll
        for (int i = 0; i < 8; ++i) { x[i] = __expf(x[i] - m); sum += x[i]; }
        #pragma unroll
        for (int off = 32; off; off >>= 1) sum += __shfl_xor(sum, off);
        float inv = 1.0f / sum;
        #pragma unroll
        for (int i = 0; i < 8; ++i) sc[b][lane + 64 * i] = x[i] * inv;
    }
    __syncthreads();

    // context[b, t, h*64+d] = sum_s p[b,s] * V[b,h,s,d]; lane = d (coalesced)
    for (int b = w; b < BATCH; b += 4) {
        const unsigned short* vp = V + (size_t)(b * NH + h) * TT * DH + lane;
        float acc = 0.f;
        for (int s = 0; s < TT; s += 4) {
            acc += sc[b][s    ] * b2f(vp[(size_t)(s    ) * DH]);
            acc += sc[b][s + 1] * b2f(vp[(size_t)(s + 1) * DH]);
            acc += sc[b][s + 2] * b2f(vp[(size_t)(s + 2) * DH]);
            acc += sc[b][s + 3] * b2f(vp[(size_t)(s + 3) * DH]);
        }
        ctx[((size_t)b * TT + t) * DM + h * DH + lane] = f2b(acc);
    }
}

// ctx (bf16 bits) @ Wo^T (f32) + bo -> float32 out
__global__ __launch_bounds__(256) void gemm_out(const unsigned short* __restrict__ A,
                                                const float* __restrict__ Bm,
                                                const float* __restrict__ bias,
                                                float* __restrict__ Cf) {
    const int K = 512, N = 512;
    int tid  = threadIdx.x;
    int w    = tid >> 6;
    int lane = tid & 63;
    int m0 = blockIdx.y * 64 + (w & 1) * 32;
    int n0 = blockIdx.x * 64 + (w >> 1) * 32;
    int mr = lane & 15;
    int kq = (lane >> 4) * 8;

    f32x4 acc[2][2] = {};
    for (int kk = 0; kk < K; kk += 32) {
        frag_cv a0c, a1c;
        a0c.u = *(const u16x8*)(A + (size_t)(m0      + mr) * K + kk + kq);
        a1c.u = *(const u16x8*)(A + (size_t)(m0 + 16 + mr) * K + kk + kq);
        bf16x8 b0 = ldf8(Bm + (size_t)(n0      + mr) * K + kk + kq);
        bf16x8 b1 = ldf8(Bm + (size_t)(n0 + 16 + mr) * K + kk + kq);
        acc[0][0] = __builtin_amdgcn_mfma_f32_16x16x32_bf16(a0c.b, b0, acc[0][0], 0, 0, 0);
        acc[0][1] = __builtin_amdgcn_mfma_f32_16x16x32_bf16(a0c.b, b1, acc[0][1], 0, 0, 0);
        acc[1][0] = __builtin_amdgcn_mfma_f32_16x16x32_bf16(a1c.b, b0, acc[1][0], 0, 0, 0);
        acc[1][1] = __builtin_amdgcn_mfma_f32_16x16x32_bf16(a1c.b, b1, acc[1][1], 0, 0, 0);
    }

    int rq = (lane >> 4) * 4;
    int cc = lane & 15;
    #pragma unroll
    for (int i = 0; i < 2; ++i) {
        #pragma unroll
        for (int j = 0; j < 2; ++j) {
            int col = n0 + j * 16 + cc;
            float bv = bias[col];
            #pragma unroll
            for (int r = 0; r < 4; ++r) {
                int row = m0 + i * 16 + rq + r;
                Cf[(size_t)row * N + col] = acc[i][j][r] + bv;
            }
        }
    }
}

extern "C" void kernel_launch(void* const* d_in, const int* in_sizes, int n_in,
                              void* d_out, int out_size, void* d_ws, size_t ws_size,
                              hipStream_t stream) {
    // Reference dtypes are float32 for ALL inputs and the output.
    const float* x    = (const float*)d_in[0];
    const float* rel  = (const float*)d_in[1];
    const float* Wq   = (const float*)d_in[2];
    const float* bq   = (const float*)d_in[3];
    const float* Wk   = (const float*)d_in[4];
    const float* bk   = (const float*)d_in[5];
    const float* Wv   = (const float*)d_in[6];
    const float* bv   = (const float*)d_in[7];
    const float* Wo   = (const float*)d_in[8];
    const float* bo   = (const float*)d_in[9];
    float* out = (float*)d_out;

    const size_t TENS = (size_t)BATCH * TT * DM;   // 2,097,152 elems
    // ws (12 MB): Q | K | ctx as bf16 bits. V (bf16, 4 MB) parks in d_out's
    // 8 MB float buffer; the final GEMM overwrites d_out after attn is done.
    unsigned short* Qw = (unsigned short*)d_ws;
    unsigned short* Kw = Qw + TENS;
    unsigned short* Cw = Kw + TENS;
    unsigned short* Vw = (unsigned short*)d_out;

    dim3 g(DM / 64, MM / 64);   // (8, 64)
    // Q scaled by 1/sqrt(DH) = 1/8 (linear, applied to xW+b)
    gemm_bt<0><<<g, 256, 0, stream>>>(x, Wq, bq, Qw, nullptr, 0.125f);
    gemm_bt<0><<<g, 256, 0, stream>>>(x, Wk, bk, Kw, nullptr, 1.0f);
    gemm_bt<0><<<g, 256, 0, stream>>>(x, Wv, bv, Vw, nullptr, 1.0f);

    attn_kernel<<<NH * TT, 256, 0, stream>>>(Qw, Kw, Vw, rel, Cw);

    gemm_out<<<g, 256, 0, stream>>>(Cw, Wo, bo, out);
}